// Round 6
// baseline (519.226 us; speedup 1.0000x reference)
//
#include <hip/hip_runtime.h>
#include <cstddef>
#include <cstdint>
#include <math.h>

// Problem constants
#define LSEQ   4096
#define BATCH  4
#define TTOK   (LSEQ * BATCH)      // 16384 rows
#define QCH    128                 // scan chunk length
#define NCH    (LSEQ / QCH)        // 32 chunks per sequence
#define NPAD   2304                // in_proj N padded to 18*128
// D_MODEL=512, D_INNER=1024, CONV_DIM=1152, NHEADS=16, HEADDIM=64, D_STATE=64
// g1out layout (ld 2304): [0,1024) z | [1024,2176) xBC | [2176,2192) dt_raw | pad
// Scan runs in reversed-time index r = 4095 - l (forward scan in r).
// Conv is anti-causal: out[l,ch] = silu(cb[ch] + sum_j cw[ch,3-j]*raw[l+j,ch]),
// tap j valid iff l+j <= 4095  <=>  j <= r.

typedef __attribute__((ext_vector_type(8))) short short8;
typedef __attribute__((ext_vector_type(8))) unsigned short ushortx8;
typedef __attribute__((ext_vector_type(4))) float floatx4;

// ---- bf16 helpers (manual, RNE) ----
__device__ __forceinline__ float bf2f(ushort u) {
    union { unsigned int i; float f; } v; v.i = ((unsigned int)u) << 16; return v.f;
}
__device__ __forceinline__ ushort f2bf(float f) {
    union { float f; unsigned int i; } v; v.f = f;
    unsigned int r = v.i + 0x7fffu + ((v.i >> 16) & 1u);
    return (ushort)(r >> 16);
}
__device__ __forceinline__ float silu_f(float a) {
    return a / (1.f + __expf(-a));
}

__device__ __forceinline__ void storev(float* p, float v)  { *p = v; }
__device__ __forceinline__ void storev(ushort* p, float v) { *p = f2bf(v); }

// async 16B global -> LDS (wave-uniform LDS base + lane*16)
__device__ __forceinline__ void gload_lds16(const ushort* g, short* l) {
    __builtin_amdgcn_global_load_lds(
        (const __attribute__((address_space(1))) void*)g,
        (__attribute__((address_space(3))) void*)l, 16, 0, 0);
}

// ---------------------------------------------------------------------------
// bf16 MFMA GEMM: C[M,N] = epi(A[M,K] @ W[N,K]^T + bias)
// EPI: 0 none, 1 silu, 2 row-scale by rsqrt(aux[row]/1024+eps)  (rms fusion)
// ---------------------------------------------------------------------------
template<int EPI, typename OutT>
__global__ __launch_bounds__(256)
void gemm_mfma(const ushort* __restrict__ A, const ushort* __restrict__ W,
               const float* __restrict__ bias, const float* __restrict__ aux,
               OutT* __restrict__ C, int M, int N, int K)
{
    __shared__ __align__(16) short As[128 * 32];
    __shared__ __align__(16) short Ws[128 * 32];
    const int tid = threadIdx.x;
    const int w = tid >> 6, l = tid & 63;
    const int m0 = blockIdx.y * 128, n0 = blockIdx.x * 128;

    const ushort* ga[2]; const ushort* gw[2];
    short* la[2]; short* lw[2];
#pragma unroll
    for (int k = 0; k < 2; ++k) {
        int row = (k * 256 + tid) >> 2;
        int c = tid & 3;
        int q = c ^ (row & 3);
        ga[k] = A + (size_t)(m0 + row) * K + q * 8;
        gw[k] = W + (size_t)(n0 + row) * K + q * 8;
        la[k] = As + (k * 64 + w * 16) * 32;
        lw[k] = Ws + (k * 64 + w * 16) * 32;
    }

    const int lm = l & 15, quad = l >> 4;
    const int wm = w & 1, wn = w >> 1;
    int aoff[4], boff[4];
#pragma unroll
    for (int i = 0; i < 4; ++i) {
        int ra = wm * 64 + i * 16 + lm;
        aoff[i] = ra * 32 + ((quad ^ (ra & 3)) * 8);
        int rb = wn * 64 + i * 16 + lm;
        boff[i] = rb * 32 + ((quad ^ (rb & 3)) * 8);
    }

    floatx4 acc[4][4];
#pragma unroll
    for (int i = 0; i < 4; ++i)
#pragma unroll
        for (int j = 0; j < 4; ++j) acc[i][j] = (floatx4){0.f, 0.f, 0.f, 0.f};

    for (int k0 = 0; k0 < K; k0 += 32) {
#pragma unroll
        for (int k = 0; k < 2; ++k) {
            gload_lds16(ga[k] + k0, la[k]);
            gload_lds16(gw[k] + k0, lw[k]);
        }
        __syncthreads();
        short8 af[4], bfr[4];
#pragma unroll
        for (int i = 0; i < 4; ++i) af[i]  = *(const short8*)(As + aoff[i]);
#pragma unroll
        for (int j = 0; j < 4; ++j) bfr[j] = *(const short8*)(Ws + boff[j]);
#pragma unroll
        for (int i = 0; i < 4; ++i)
#pragma unroll
            for (int j = 0; j < 4; ++j)
                acc[i][j] = __builtin_amdgcn_mfma_f32_16x16x32_bf16(
                    af[i], bfr[j], acc[i][j], 0, 0, 0);
        __syncthreads();
    }

#pragma unroll
    for (int i = 0; i < 4; ++i) {
        const int rbase = m0 + wm * 64 + i * 16 + quad * 4;
#pragma unroll
        for (int r = 0; r < 4; ++r) {
            float scale = 1.f;
            if (EPI == 2) scale = rsqrtf(aux[rbase + r] * (1.f / 1024.f) + 1e-5f);
#pragma unroll
            for (int j = 0; j < 4; ++j) {
                const int col = n0 + wn * 64 + j * 16 + lm;
                float v = acc[i][j][r];
                if (bias) v += bias[col];
                if (EPI == 1) v = silu_f(v);
                if (EPI == 2) v *= scale;
                storev(&C[(size_t)(rbase + r) * N + col], v);
            }
        }
    }
}

// ---------------------------------------------------------------------------
// casts
// ---------------------------------------------------------------------------
__global__ __launch_bounds__(256)
void cast_x_k(const float4* __restrict__ in, ushort4* __restrict__ out, int n4)
{
    int i = blockIdx.x * 256 + threadIdx.x;
    if (i >= n4) return;
    float4 v = in[i];
    ushort4 o;
    o.x = f2bf(v.x); o.y = f2bf(v.y); o.z = f2bf(v.z); o.w = f2bf(v.w);
    out[i] = o;
}

// all weight preps in one launch:
//   [0, 2304*512)       in_proj pad+cast -> wip
//   [+, 1024*512)       w1 fold+cast     -> w1eb
//   [+, 512*1024)       out_proj * rms_w cast -> wopb  (rms fusion)
//   [+, 512*1024)       w2 cast          -> w2b
__global__ __launch_bounds__(256)
void prep_weights(const float* __restrict__ ipw, const float* __restrict__ w1,
                  const float* __restrict__ wop, const float* __restrict__ w2,
                  const float* __restrict__ rw,
                  ushort* __restrict__ wip, ushort* __restrict__ w1eb,
                  ushort* __restrict__ wopb, ushort* __restrict__ w2b)
{
    int i4 = (blockIdx.x * 256 + threadIdx.x) * 4;
    if (i4 < NPAD * 512) {
        int row = i4 >> 9;
        ushort4 v;
        if (row < 2192) {
            float4 s = *(const float4*)(ipw + (size_t)i4);
            v.x = f2bf(s.x); v.y = f2bf(s.y); v.z = f2bf(s.z); v.w = f2bf(s.w);
        } else { v.x = v.y = v.z = v.w = 0; }
        *(ushort4*)(wip + i4) = v;
        return;
    }
    i4 -= NPAD * 512;
    if (i4 < 1024 * 512) {
        int j = i4 >> 9, d = i4 & 511;
        float4 a = *(const float4*)(w1 + (size_t)j * 1024 + d);
        float4 b = *(const float4*)(w1 + (size_t)j * 1024 + 512 + d);
        ushort4 v;
        v.x = f2bf(a.x + b.x); v.y = f2bf(a.y + b.y);
        v.z = f2bf(a.z + b.z); v.w = f2bf(a.w + b.w);
        *(ushort4*)(w1eb + i4) = v;
        return;
    }
    i4 -= 1024 * 512;
    if (i4 < 512 * 1024) {
        float4 s = *(const float4*)(wop + (size_t)i4);
        float4 g = *(const float4*)(rw + (i4 & 1023));
        ushort4 v;
        v.x = f2bf(s.x * g.x); v.y = f2bf(s.y * g.y);
        v.z = f2bf(s.z * g.z); v.w = f2bf(s.w * g.w);
        *(ushort4*)(wopb + i4) = v;
        return;
    }
    i4 -= 512 * 1024;
    if (i4 < 512 * 1024) {
        float4 s = *(const float4*)(w2 + (size_t)i4);
        ushort4 v;
        v.x = f2bf(s.x); v.y = f2bf(s.y); v.z = f2bf(s.z); v.w = f2bf(s.w);
        *(ushort4*)(w2b + i4) = v;
    }
}

// ---------------------------------------------------------------------------
// seg_scan (dt fused): per chunk of 128 scan-steps,
//   v = raw_dt + dt_bias; dt = softplus(v); lda = dt * (-exp(A_log))
//   seg = inclusive cumsum(lda); alpha = exp(seg_last - seg)*dt; P = exp(seg_last)
// ---------------------------------------------------------------------------
__global__ __launch_bounds__(128)
void seg_scan(const ushort* __restrict__ raw, const float* __restrict__ dt_bias,
              const float* __restrict__ A_log, float* __restrict__ dtr,
              float* __restrict__ segb, float* __restrict__ alphab,
              float* __restrict__ Pb)
{
    __shared__ float s[128];
    const int tid = threadIdx.x;
    const int c = blockIdx.x, h = blockIdx.y, b = blockIdx.z;
    const int bh = b * 16 + h;
    const int r = c * QCH + tid;
    const size_t grow = (size_t)b * LSEQ + (LSEQ - 1 - r);
    const size_t idx = (size_t)bh * LSEQ + r;

    float v = bf2f(raw[grow * NPAD + 2176 + h]) + dt_bias[h];
    float dt = (v > 20.f) ? v : log1pf(expf(v));
    float Ah = -expf(A_log[h]);
    s[tid] = dt * Ah;
    __syncthreads();
#pragma unroll
    for (int off = 1; off < 128; off <<= 1) {
        float t = (tid >= off) ? s[tid - off] : 0.f;
        __syncthreads();
        s[tid] += t;
        __syncthreads();
    }
    float seg = s[tid];
    float last = s[127];
    dtr[idx] = dt;
    segb[idx] = seg;
    alphab[idx] = __expf(last - seg) * dt;
    if (tid == 127) Pb[bh * NCH + c] = __expf(last);
}

// ---------------------------------------------------------------------------
// SSD pass A with FUSED conv+silu staging: per tile (c,h,b),
//   L[p,n] = sum_tau XT[p,tau] * (alpha(tau)*B[tau,n])
// Thread (tid&15) owns a fixed 4-channel quad; conv weights live in registers.
// ---------------------------------------------------------------------------
__global__ __launch_bounds__(256)
void ssd_states(const ushort* __restrict__ raw, const float* __restrict__ cw,
                const float* __restrict__ cb, const float* __restrict__ alphab,
                float* __restrict__ sbuf)
{
    __shared__ __align__(16) ushort XT[64 * 136];
    __shared__ __align__(16) ushort BpT[64 * 136];
    const int tid = threadIdx.x;
    const int w = tid >> 6, lane = tid & 63;
    const int lm = lane & 15, quad = lane >> 4;
    const int c = blockIdx.x, h = blockIdx.y, b = blockIdx.z;
    const int bh = b * 16 + h;
    const size_t abase = (size_t)bh * LSEQ + c * QCH;

    const int e4 = (tid & 15) * 4;
    const int colx = 1024 + h * 64 + e4;   // raw col of X quad
    const int colb = 2048 + e4;            // raw col of B quad
    float wx[4][4], wb[4][4];
#pragma unroll
    for (int e = 0; e < 4; ++e) {
        float4 a = *(const float4*)(cw + (h * 64 + e4 + e) * 4);
        wx[0][e] = a.w; wx[1][e] = a.z; wx[2][e] = a.y; wx[3][e] = a.x;
        float4 bw = *(const float4*)(cw + (1024 + e4 + e) * 4);
        wb[0][e] = bw.w; wb[1][e] = bw.z; wb[2][e] = bw.y; wb[3][e] = bw.x;
    }
    const float4 bx4 = *(const float4*)(cb + h * 64 + e4);
    const float4 bb4 = *(const float4*)(cb + 1024 + e4);

#pragma unroll
    for (int it = 0; it < 8; ++it) {
        const int tau = it * 16 + (tid >> 4);
        const int r = c * QCH + tau;
        const size_t grow = (size_t)b * LSEQ + (LSEQ - 1 - r);
        float ax[4] = {bx4.x, bx4.y, bx4.z, bx4.w};
        float ab[4] = {bb4.x, bb4.y, bb4.z, bb4.w};
#pragma unroll
        for (int j = 0; j < 4; ++j) {
            if (j <= r) {
                const ushort* rp = raw + (grow + j) * NPAD;
                ushort4 xv = *(const ushort4*)(rp + colx);
                ushort4 bv = *(const ushort4*)(rp + colb);
                ax[0] = fmaf(wx[j][0], bf2f(xv.x), ax[0]);
                ax[1] = fmaf(wx[j][1], bf2f(xv.y), ax[1]);
                ax[2] = fmaf(wx[j][2], bf2f(xv.z), ax[2]);
                ax[3] = fmaf(wx[j][3], bf2f(xv.w), ax[3]);
                ab[0] = fmaf(wb[j][0], bf2f(bv.x), ab[0]);
                ab[1] = fmaf(wb[j][1], bf2f(bv.y), ab[1]);
                ab[2] = fmaf(wb[j][2], bf2f(bv.z), ab[2]);
                ab[3] = fmaf(wb[j][3], bf2f(bv.w), ab[3]);
            }
        }
        const float al = alphab[abase + tau];
#pragma unroll
        for (int e = 0; e < 4; ++e) {
            XT[(e4 + e) * 136 + tau]  = f2bf(silu_f(ax[e]));
            BpT[(e4 + e) * 136 + tau] = f2bf(silu_f(ab[e]) * al);
        }
    }
    __syncthreads();

    floatx4 L[4];
#pragma unroll
    for (int j = 0; j < 4; ++j) L[j] = (floatx4){0.f, 0.f, 0.f, 0.f};
#pragma unroll
    for (int kc = 0; kc < 4; ++kc) {
        short8 a = *(const short8*)(XT + (w * 16 + lm) * 136 + kc * 32 + quad * 8);
#pragma unroll
        for (int jn = 0; jn < 4; ++jn) {
            short8 bf = *(const short8*)(BpT + (jn * 16 + lm) * 136 + kc * 32 + quad * 8);
            L[jn] = __builtin_amdgcn_mfma_f32_16x16x32_bf16(a, bf, L[jn], 0, 0, 0);
        }
    }
    float* Sp = sbuf + ((size_t)bh * NCH + c) * 4096;
#pragma unroll
    for (int jn = 0; jn < 4; ++jn)
#pragma unroll
        for (int r = 0; r < 4; ++r) {
            int p = w * 16 + quad * 4 + r;
            Sp[p * 64 + jn * 16 + lm] = L[jn][r];
        }
}

// ---------------------------------------------------------------------------
// Combine: sequential over chunks in scan (r) order, prefetched.
// Also zeroes the per-row ssq accumulator for the rms fusion (16384 floats).
// ---------------------------------------------------------------------------
__global__ __launch_bounds__(256)
void scan_combine(float* __restrict__ sbuf, const float* __restrict__ Pb,
                  float* __restrict__ ssq)
{
    const int tid = threadIdx.x;
    const int h = blockIdx.y, b = blockIdx.z;
    const int bh = b * 16 + h;
    ssq[(size_t)bh * 256 + tid] = 0.f;
    const int off = tid * 16;
    float carry[16];
#pragma unroll
    for (int j = 0; j < 16; ++j) carry[j] = 0.f;

    float* sp0 = sbuf + (size_t)bh * NCH * 4096 + off;
    float4 n0 = *(const float4*)(sp0 + 0);
    float4 n1 = *(const float4*)(sp0 + 4);
    float4 n2 = *(const float4*)(sp0 + 8);
    float4 n3 = *(const float4*)(sp0 + 12);
    float Pn = Pb[bh * NCH];

    for (int c = 0; c < NCH; ++c) {
        float4 l0 = n0, l1 = n1, l2 = n2, l3 = n3;
        float P = Pn;
        if (c + 1 < NCH) {
            const float* spn = sp0 + (size_t)(c + 1) * 4096;
            n0 = *(const float4*)(spn + 0);
            n1 = *(const float4*)(spn + 4);
            n2 = *(const float4*)(spn + 8);
            n3 = *(const float4*)(spn + 12);
            Pn = Pb[bh * NCH + c + 1];
        }
        float* sp = sp0 + (size_t)c * 4096;
        *(float4*)(sp + 0)  = make_float4(carry[0],  carry[1],  carry[2],  carry[3]);
        *(float4*)(sp + 4)  = make_float4(carry[4],  carry[5],  carry[6],  carry[7]);
        *(float4*)(sp + 8)  = make_float4(carry[8],  carry[9],  carry[10], carry[11]);
        *(float4*)(sp + 12) = make_float4(carry[12], carry[13], carry[14], carry[15]);
        float lv[16] = {l0.x, l0.y, l0.z, l0.w, l1.x, l1.y, l1.z, l1.w,
                        l2.x, l2.y, l2.z, l2.w, l3.x, l3.y, l3.z, l3.w};
#pragma unroll
        for (int j = 0; j < 16; ++j) carry[j] = fmaf(carry[j], P, lv[j]);
    }
}

// ---------------------------------------------------------------------------
// SSD pass C with FUSED conv+silu staging and FUSED rms partial-sum:
//   Y = [M o (C B^T)] X + diag(exp(seg)) C h_start^T, D on diagonal,
//   z-gate fused, writes gated bf16 + atomic per-row sum of squares.
// ---------------------------------------------------------------------------
__global__ __launch_bounds__(256)
void ssd_y(const ushort* __restrict__ raw, const float* __restrict__ cw,
           const float* __restrict__ cb,
           const float* __restrict__ segb, const float* __restrict__ dtb_,
           const float* __restrict__ Dvec, const float* __restrict__ sbuf,
           ushort* __restrict__ gz, float* __restrict__ ssq)
{
    __shared__ __align__(16) char smem[72192];
    ushort* Ct  = (ushort*)smem;            // [128][72]
    ushort* XT  = (ushort*)(smem + 18432);  // [64][136]
    ushort* Bt  = (ushort*)(smem + 35840);  // [128][72]  (dead after GEMM1)
    ushort* Wl  = (ushort*)(smem + 35840);  // [128][136] (overlaps Bt)
    float* segl = (float*)(smem + 70656);   // [128]
    float* dtl  = (float*)(smem + 71168);   // [128]

    const int tid = threadIdx.x;
    const int w = tid >> 6, lane = tid & 63;
    const int lm = lane & 15, quad = lane >> 4;
    const int c = blockIdx.x, h = blockIdx.y, b = blockIdx.z;
    const int bh = b * 16 + h;
    const size_t abase = (size_t)bh * LSEQ + c * QCH;

    if (tid < 128) {
        segl[tid] = segb[abase + tid];
        dtl[tid]  = dtb_[abase + tid];
    }

    const int e4 = (tid & 15) * 4;
    const int colx = 1024 + h * 64 + e4;
    const int colb = 2048 + e4;
    const int colc = 2112 + e4;
    float wx[4][4], wb[4][4], wc[4][4];
#pragma unroll
    for (int e = 0; e < 4; ++e) {
        float4 a = *(const float4*)(cw + (h * 64 + e4 + e) * 4);
        wx[0][e] = a.w; wx[1][e] = a.z; wx[2][e] = a.y; wx[3][e] = a.x;
        float4 bw = *(const float4*)(cw + (1024 + e4 + e) * 4);
        wb[0][e] = bw.w; wb[1][e] = bw.z; wb[2][e] = bw.y; wb[3][e] = bw.x;
        float4 cc = *(const float4*)(cw + (1088 + e4 + e) * 4);
        wc[0][e] = cc.w; wc[1][e] = cc.z; wc[2][e] = cc.y; wc[3][e] = cc.x;
    }
    const float4 bx4 = *(const float4*)(cb + h * 64 + e4);
    const float4 bb4 = *(const float4*)(cb + 1024 + e4);
    const float4 bc4 = *(const float4*)(cb + 1088 + e4);

#pragma unroll
    for (int it = 0; it < 8; ++it) {
        const int tau = it * 16 + (tid >> 4);
        const int r = c * QCH + tau;
        const size_t grow = (size_t)b * LSEQ + (LSEQ - 1 - r);
        float ax[4] = {bx4.x, bx4.y, bx4.z, bx4.w};
        float ab[4] = {bb4.x, bb4.y, bb4.z, bb4.w};
        float ac[4] = {bc4.x, bc4.y, bc4.z, bc4.w};
#pragma unroll
        for (int j = 0; j < 4; ++j) {
            if (j <= r) {
                const ushort* rp = raw + (grow + j) * NPAD;
                ushort4 xv = *(const ushort4*)(rp + colx);
                ushort4 bv = *(const ushort4*)(rp + colb);
                ushort4 cv = *(const ushort4*)(rp + colc);
                ax[0] = fmaf(wx[j][0], bf2f(xv.x), ax[0]);
                ax[1] = fmaf(wx[j][1], bf2f(xv.y), ax[1]);
                ax[2] = fmaf(wx[j][2], bf2f(xv.z), ax[2]);
                ax[3] = fmaf(wx[j][3], bf2f(xv.w), ax[3]);
                ab[0] = fmaf(wb[j][0], bf2f(bv.x), ab[0]);
                ab[1] = fmaf(wb[j][1], bf2f(bv.y), ab[1]);
                ab[2] = fmaf(wb[j][2], bf2f(bv.z), ab[2]);
                ab[3] = fmaf(wb[j][3], bf2f(bv.w), ab[3]);
                ac[0] = fmaf(wc[j][0], bf2f(cv.x), ac[0]);
                ac[1] = fmaf(wc[j][1], bf2f(cv.y), ac[1]);
                ac[2] = fmaf(wc[j][2], bf2f(cv.z), ac[2]);
                ac[3] = fmaf(wc[j][3], bf2f(cv.w), ac[3]);
            }
        }
        ushort4 bo, co;
        bo.x = f2bf(silu_f(ab[0])); bo.y = f2bf(silu_f(ab[1]));
        bo.z = f2bf(silu_f(ab[2])); bo.w = f2bf(silu_f(ab[3]));
        co.x = f2bf(silu_f(ac[0])); co.y = f2bf(silu_f(ac[1]));
        co.z = f2bf(silu_f(ac[2])); co.w = f2bf(silu_f(ac[3]));
        *(ushort4*)(Bt + tau * 72 + e4) = bo;
        *(ushort4*)(Ct + tau * 72 + e4) = co;
#pragma unroll
        for (int e = 0; e < 4; ++e)
            XT[(e4 + e) * 136 + tau] = f2bf(silu_f(ax[e]));
    }
    __syncthreads();

    // GEMM1: G = C . B^T ; wave w owns rows [w*32,+32)
    floatx4 G[2][8];
#pragma unroll
    for (int i = 0; i < 2; ++i)
#pragma unroll
        for (int j = 0; j < 8; ++j) G[i][j] = (floatx4){0.f, 0.f, 0.f, 0.f};
#pragma unroll
    for (int kc = 0; kc < 2; ++kc) {
        short8 a[2];
#pragma unroll
        for (int i = 0; i < 2; ++i)
            a[i] = *(const short8*)(Ct + (w * 32 + i * 16 + lm) * 72 + kc * 32 + quad * 8);
#pragma unroll
        for (int jn = 0; jn < 8; ++jn) {
            short8 bf = *(const short8*)(Bt + (jn * 16 + lm) * 72 + kc * 32 + quad * 8);
#pragma unroll
            for (int i = 0; i < 2; ++i)
                G[i][jn] = __builtin_amdgcn_mfma_f32_16x16x32_bf16(a[i], bf, G[i][jn], 0, 0, 0);
        }
    }
    __syncthreads();   // everyone done reading Bt before Wl overwrites it

    const float Dh = Dvec[h];
#pragma unroll
    for (int i = 0; i < 2; ++i) {
        const int taub = w * 32 + i * 16;
#pragma unroll
        for (int jn = 0; jn < 8; ++jn) {
            const int sigma = jn * 16 + lm;
            const float dts = dtl[sigma];
            const float segs = segl[sigma];
#pragma unroll
            for (int r = 0; r < 4; ++r) {
                const int tau = taub + quad * 4 + r;
                float g = G[i][jn][r];
                float wv;
                if (sigma < tau)       wv = dts * g * __expf(segl[tau] - segs);
                else if (sigma == tau) wv = dts * g + Dh;
                else                   wv = 0.f;
                Wl[tau * 136 + sigma] = f2bf(wv);
            }
        }
    }
    // no barrier needed: each wave reads back only its own W rows

    // GEMM2: Y = W.X + (exp(seg) C).H^T
    floatx4 Y[2][4];
#pragma unroll
    for (int i = 0; i < 2; ++i)
#pragma unroll
        for (int j = 0; j < 4; ++j) Y[i][j] = (floatx4){0.f, 0.f, 0.f, 0.f};
#pragma unroll
    for (int kc = 0; kc < 4; ++kc) {
        short8 a[2];
#pragma unroll
        for (int i = 0; i < 2; ++i)
            a[i] = *(const short8*)(Wl + (w * 32 + i * 16 + lm) * 136 + kc * 32 + quad * 8);
#pragma unroll
        for (int jn = 0; jn < 4; ++jn) {
            short8 bf = *(const short8*)(XT + (jn * 16 + lm) * 136 + kc * 32 + quad * 8);
#pragma unroll
            for (int i = 0; i < 2; ++i)
                Y[i][jn] = __builtin_amdgcn_mfma_f32_16x16x32_bf16(a[i], bf, Y[i][jn], 0, 0, 0);
        }
    }
    const float* Hp = sbuf + ((size_t)bh * NCH + c) * 4096;
#pragma unroll
    for (int kc = 0; kc < 2; ++kc) {
        short8 a[2];
#pragma unroll
        for (int i = 0; i < 2; ++i) {
            const int row = w * 32 + i * 16 + lm;
            const float es = __expf(segl[row]);
            short8 craw = *(const short8*)(Ct + row * 72 + kc * 32 + quad * 8);
#pragma unroll
            for (int e = 0; e < 8; ++e)
                a[i][e] = (short)f2bf(bf2f((ushort)craw[e]) * es);
        }
#pragma unroll
        for (int jn = 0; jn < 4; ++jn) {
            const float* hp = Hp + (jn * 16 + lm) * 64 + kc * 32 + quad * 8;
            float4 h0 = *(const float4*)(hp);
            float4 h1 = *(const float4*)(hp + 4);
            short8 bf;
            bf[0] = (short)f2bf(h0.x); bf[1] = (short)f2bf(h0.y);
            bf[2] = (short)f2bf(h0.z); bf[3] = (short)f2bf(h0.w);
            bf[4] = (short)f2bf(h1.x); bf[5] = (short)f2bf(h1.y);
            bf[6] = (short)f2bf(h1.z); bf[7] = (short)f2bf(h1.w);
#pragma unroll
            for (int i = 0; i < 2; ++i)
                Y[i][jn] = __builtin_amdgcn_mfma_f32_16x16x32_bf16(a[i], bf, Y[i][jn], 0, 0, 0);
        }
    }

    // epilogue: z-gate, store gated bf16, accumulate per-row sum of squares
#pragma unroll
    for (int i = 0; i < 2; ++i) {
#pragma unroll
        for (int r = 0; r < 4; ++r) {
            const int tau = w * 32 + i * 16 + quad * 4 + r;
            const size_t grow = (size_t)b * LSEQ + (LSEQ - 1 - (c * QCH + tau));
            float part = 0.f;
#pragma unroll
            for (int jn = 0; jn < 4; ++jn) {
                const int col = h * 64 + jn * 16 + lm;
                float yv = Y[i][jn][r];
                float zv = bf2f(raw[grow * NPAD + col]);
                float gv = yv * silu_f(zv);
                gz[grow * 1024 + col] = f2bf(gv);
                part += gv * gv;
            }
            part += __shfl_xor(part, 1);
            part += __shfl_xor(part, 2);
            part += __shfl_xor(part, 4);
            part += __shfl_xor(part, 8);
            if (lm == 0) atomicAdd(ssq + grow, part);
        }
    }
}

// ---------------------------------------------------------------------------
// LayerNorm over 512, fp32 in, bf16 out
// ---------------------------------------------------------------------------
__global__ __launch_bounds__(256)
void layernorm_k(const float* __restrict__ x, const float* __restrict__ gg,
                 const float* __restrict__ bb, ushort* __restrict__ out)
{
    const int row = blockIdx.x;
    const int tid = threadIdx.x;
    float x0 = x[(size_t)row * 512 + tid];
    float x1 = x[(size_t)row * 512 + 256 + tid];
    float s = x0 + x1, ss = x0 * x0 + x1 * x1;
#pragma unroll
    for (int off = 32; off > 0; off >>= 1) {
        s += __shfl_xor(s, off);
        ss += __shfl_xor(ss, off);
    }
    __shared__ float rs[4], rss[4];
    if ((tid & 63) == 0) { rs[tid >> 6] = s; rss[tid >> 6] = ss; }
    __syncthreads();
    s = rs[0] + rs[1] + rs[2] + rs[3];
    ss = rss[0] + rss[1] + rss[2] + rss[3];
    const float mean = s * (1.f / 512.f);
    const float var = ss * (1.f / 512.f) - mean * mean;
    const float inv = rsqrtf(var + 1e-5f);
    out[(size_t)row * 512 + tid]       = f2bf((x0 - mean) * inv * gg[tid] + bb[tid]);
    out[(size_t)row * 512 + 256 + tid] = f2bf((x1 - mean) * inv * gg[256 + tid] + bb[256 + tid]);
}

// ---------------------------------------------------------------------------
extern "C" void kernel_launch(void* const* d_in, const int* in_sizes, int n_in,
                              void* d_out, int out_size, void* d_ws, size_t ws_size,
                              hipStream_t stream)
{
    const float* x         = (const float*)d_in[0];
    const float* in_proj_w = (const float*)d_in[1];   // (2192, 512)
    const float* conv_w    = (const float*)d_in[2];   // (1152, 4)
    const float* conv_b    = (const float*)d_in[3];
    const float* dt_bias   = (const float*)d_in[4];   // (16,)
    const float* A_log     = (const float*)d_in[5];
    const float* Dv        = (const float*)d_in[6];
    const float* rms_w     = (const float*)d_in[7];
    const float* out_proj_w= (const float*)d_in[8];   // (512, 1024)
    const float* ln_g      = (const float*)d_in[9];
    const float* ln_b      = (const float*)d_in[10];
    const float* w1        = (const float*)d_in[11];  // (1024, 1024)
    const float* b1        = (const float*)d_in[12];
    const float* w2        = (const float*)d_in[13];  // (512, 1024)
    const float* b2        = (const float*)d_in[14];
    float* out = (float*)d_out;
    char* base = (char*)d_ws;

    // workspace layout (byte offsets), liveness-safe reuse:
    ushort* g1out = (ushort*)(base);                   // [T,2304] bf16   75.5 MB
    ushort* gz    = (ushort*)(base + 113246208);       // [T,1024] bf16   33.5 MB
    ushort* xbf   = (ushort*)(base + 113246208);       // [T,512] bf16 (dead before gz)
    float*  dtr   = (float*) (base + 146800640);       // [64][4096]       1 MB
    float*  segb  = (float*) (base + 148897792);       // [64][4096]       1 MB
    float*  alphab= (float*) (base + 149946368);       // [64][4096]       1 MB
    ushort* wip   = (ushort*)(base + 150994944);       // [2304,512] bf16
    ushort* w1eb  = (ushort*)(base + 153354240);       // [1024,512] bf16
    ushort* wopb  = (ushort*)(base + 154402816);       // [512,1024] bf16
    ushort* w2b   = (ushort*)(base + 155451392);       // [512,1024] bf16
    float*  Pbuf  = (float*) (base + 156499968);       // [2048]
    float*  ssqp  = (float*) (base + 156508160);       // [16384] rms partials
    // post-scan reuse:
    float*  y2  = (float*)base;                        // [T,512] f32 (g1out dead)
    ushort* yln = (ushort*)(base + 33554432);          // [T,512] bf16
    ushort* h1  = gz;                                  // [T,1024] bf16 (gz dead after out_proj)
    // chunk states: 64 tiles/seq-head x 4096 f32 == out_size; d_out dead until MLP2
    float* sbuf = out;

    // ---- casts ----
    cast_x_k<<<(TTOK * 512 / 4 + 255) / 256, 256, 0, stream>>>(
        (const float4*)x, (ushort4*)xbf, TTOK * 512 / 4);
    prep_weights<<<((NPAD * 512 + 1024 * 512 + 2 * 512 * 1024) / 4 + 255) / 256, 256, 0, stream>>>(
        in_proj_w, w1, out_proj_w, w2, rms_w, wip, w1eb, wopb, w2b);

    // ---- in_proj ----
    gemm_mfma<0, ushort><<<dim3(NPAD / 128, TTOK / 128), 256, 0, stream>>>(
        xbf, wip, nullptr, nullptr, g1out, TTOK, NPAD, 512);

    seg_scan<<<dim3(NCH, 16, 4), 128, 0, stream>>>(g1out, dt_bias, A_log, dtr, segb, alphab, Pbuf);

    // ---- SSD chunked scan (conv+silu fused into staging) ----
    ssd_states  <<<dim3(NCH, 16, 4), 256, 0, stream>>>(g1out, conv_w, conv_b, alphab, sbuf);
    scan_combine<<<dim3(1, 16, 4),   256, 0, stream>>>(sbuf, Pbuf, ssqp);
    ssd_y       <<<dim3(NCH, 16, 4), 256, 0, stream>>>(g1out, conv_w, conv_b, segb, dtr, Dv,
                                                       sbuf, gz, ssqp);

    // ---- projections + MLP (rms fused into out_proj) ----
    gemm_mfma<2, float><<<dim3(512 / 128, TTOK / 128), 256, 0, stream>>>(
        gz, wopb, nullptr, ssqp, y2, TTOK, 512, 1024);
    layernorm_k<<<TTOK, 256, 0, stream>>>(y2, ln_g, ln_b, yln);
    gemm_mfma<1, ushort><<<dim3(1024 / 128, TTOK / 128), 256, 0, stream>>>(
        yln, w1eb, b1, nullptr, h1, TTOK, 1024, 512);
    gemm_mfma<0, float><<<dim3(512 / 128, TTOK / 128), 256, 0, stream>>>(
        h1, w2b, b2, nullptr, out, TTOK, 512, 1024);
}

// Round 7
// 462.410 us; speedup vs baseline: 1.1229x; 1.1229x over previous
//
#include <hip/hip_runtime.h>
#include <cstddef>
#include <cstdint>
#include <math.h>

// Problem constants
#define LSEQ   4096
#define BATCH  4
#define TTOK   (LSEQ * BATCH)      // 16384 rows
#define QCH    128                 // scan chunk length
#define NCH    (LSEQ / QCH)        // 32 chunks per sequence
#define NPAD   2304                // in_proj N padded to 18*128
// D_MODEL=512, D_INNER=1024, CONV_DIM=1152, NHEADS=16, HEADDIM=64, D_STATE=64
// g1out layout (ld 2304): [0,1024) z | [1024,2176) xBC | [2176,2192) dt_raw | pad
// Scan runs in reversed-time index r = 4095 - l (forward scan in r).
// Conv is anti-causal: out[l,ch] = silu(cb[ch] + sum_j cw[ch,3-j]*raw[l+j,ch]),
// tap j valid iff l+j <= 4095.

typedef __attribute__((ext_vector_type(8))) short short8;
typedef __attribute__((ext_vector_type(8))) unsigned short ushortx8;
typedef __attribute__((ext_vector_type(4))) float floatx4;

// ---- bf16 helpers (manual, RNE) ----
__device__ __forceinline__ float bf2f(ushort u) {
    union { unsigned int i; float f; } v; v.i = ((unsigned int)u) << 16; return v.f;
}
__device__ __forceinline__ ushort f2bf(float f) {
    union { float f; unsigned int i; } v; v.f = f;
    unsigned int r = v.i + 0x7fffu + ((v.i >> 16) & 1u);
    return (ushort)(r >> 16);
}
__device__ __forceinline__ float silu_f(float a) {
    return a / (1.f + __expf(-a));
}

__device__ __forceinline__ void storev(float* p, float v)  { *p = v; }
__device__ __forceinline__ void storev(ushort* p, float v) { *p = f2bf(v); }

// async 16B global -> LDS (wave-uniform LDS base + lane*16)
__device__ __forceinline__ void gload_lds16(const ushort* g, short* l) {
    __builtin_amdgcn_global_load_lds(
        (const __attribute__((address_space(1))) void*)g,
        (__attribute__((address_space(3))) void*)l, 16, 0, 0);
}

// ---------------------------------------------------------------------------
// bf16 MFMA GEMM: C[M,N] = epi(A[M,K] @ W[N,K]^T + bias)
// EPI: 0 none, 1 silu, 2 row-scale by rsqrt(aux[row]/1024+eps)  (rms fusion)
// ---------------------------------------------------------------------------
template<int EPI, typename OutT>
__global__ __launch_bounds__(256)
void gemm_mfma(const ushort* __restrict__ A, const ushort* __restrict__ W,
               const float* __restrict__ bias, const float* __restrict__ aux,
               OutT* __restrict__ C, int M, int N, int K)
{
    __shared__ __align__(16) short As[128 * 32];
    __shared__ __align__(16) short Ws[128 * 32];
    const int tid = threadIdx.x;
    const int w = tid >> 6, l = tid & 63;
    const int m0 = blockIdx.y * 128, n0 = blockIdx.x * 128;

    const ushort* ga[2]; const ushort* gw[2];
    short* la[2]; short* lw[2];
#pragma unroll
    for (int k = 0; k < 2; ++k) {
        int row = (k * 256 + tid) >> 2;
        int c = tid & 3;
        int q = c ^ (row & 3);
        ga[k] = A + (size_t)(m0 + row) * K + q * 8;
        gw[k] = W + (size_t)(n0 + row) * K + q * 8;
        la[k] = As + (k * 64 + w * 16) * 32;
        lw[k] = Ws + (k * 64 + w * 16) * 32;
    }

    const int lm = l & 15, quad = l >> 4;
    const int wm = w & 1, wn = w >> 1;
    int aoff[4], boff[4];
#pragma unroll
    for (int i = 0; i < 4; ++i) {
        int ra = wm * 64 + i * 16 + lm;
        aoff[i] = ra * 32 + ((quad ^ (ra & 3)) * 8);
        int rb = wn * 64 + i * 16 + lm;
        boff[i] = rb * 32 + ((quad ^ (rb & 3)) * 8);
    }

    floatx4 acc[4][4];
#pragma unroll
    for (int i = 0; i < 4; ++i)
#pragma unroll
        for (int j = 0; j < 4; ++j) acc[i][j] = (floatx4){0.f, 0.f, 0.f, 0.f};

    for (int k0 = 0; k0 < K; k0 += 32) {
#pragma unroll
        for (int k = 0; k < 2; ++k) {
            gload_lds16(ga[k] + k0, la[k]);
            gload_lds16(gw[k] + k0, lw[k]);
        }
        __syncthreads();
        short8 af[4], bfr[4];
#pragma unroll
        for (int i = 0; i < 4; ++i) af[i]  = *(const short8*)(As + aoff[i]);
#pragma unroll
        for (int j = 0; j < 4; ++j) bfr[j] = *(const short8*)(Ws + boff[j]);
#pragma unroll
        for (int i = 0; i < 4; ++i)
#pragma unroll
            for (int j = 0; j < 4; ++j)
                acc[i][j] = __builtin_amdgcn_mfma_f32_16x16x32_bf16(
                    af[i], bfr[j], acc[i][j], 0, 0, 0);
        __syncthreads();
    }

#pragma unroll
    for (int i = 0; i < 4; ++i) {
        const int rbase = m0 + wm * 64 + i * 16 + quad * 4;
#pragma unroll
        for (int r = 0; r < 4; ++r) {
            float scale = 1.f;
            if (EPI == 2) scale = rsqrtf(aux[rbase + r] * (1.f / 1024.f) + 1e-5f);
#pragma unroll
            for (int j = 0; j < 4; ++j) {
                const int col = n0 + wn * 64 + j * 16 + lm;
                float v = acc[i][j][r];
                if (bias) v += bias[col];
                if (EPI == 1) v = silu_f(v);
                if (EPI == 2) v *= scale;
                storev(&C[(size_t)(rbase + r) * N + col], v);
            }
        }
    }
}

// ---------------------------------------------------------------------------
// casts
// ---------------------------------------------------------------------------
__global__ __launch_bounds__(256)
void cast_x_k(const float4* __restrict__ in, ushort4* __restrict__ out, int n4)
{
    int i = blockIdx.x * 256 + threadIdx.x;
    if (i >= n4) return;
    float4 v = in[i];
    ushort4 o;
    o.x = f2bf(v.x); o.y = f2bf(v.y); o.z = f2bf(v.z); o.w = f2bf(v.w);
    out[i] = o;
}

// all weight preps in one launch (in_proj pad, w1 fold, out_proj*rms_w, w2)
__global__ __launch_bounds__(256)
void prep_weights(const float* __restrict__ ipw, const float* __restrict__ w1,
                  const float* __restrict__ wop, const float* __restrict__ w2,
                  const float* __restrict__ rw,
                  ushort* __restrict__ wip, ushort* __restrict__ w1eb,
                  ushort* __restrict__ wopb, ushort* __restrict__ w2b)
{
    int i4 = (blockIdx.x * 256 + threadIdx.x) * 4;
    if (i4 < NPAD * 512) {
        int row = i4 >> 9;
        ushort4 v;
        if (row < 2192) {
            float4 s = *(const float4*)(ipw + (size_t)i4);
            v.x = f2bf(s.x); v.y = f2bf(s.y); v.z = f2bf(s.z); v.w = f2bf(s.w);
        } else { v.x = v.y = v.z = v.w = 0; }
        *(ushort4*)(wip + i4) = v;
        return;
    }
    i4 -= NPAD * 512;
    if (i4 < 1024 * 512) {
        int j = i4 >> 9, d = i4 & 511;
        float4 a = *(const float4*)(w1 + (size_t)j * 1024 + d);
        float4 b = *(const float4*)(w1 + (size_t)j * 1024 + 512 + d);
        ushort4 v;
        v.x = f2bf(a.x + b.x); v.y = f2bf(a.y + b.y);
        v.z = f2bf(a.z + b.z); v.w = f2bf(a.w + b.w);
        *(ushort4*)(w1eb + i4) = v;
        return;
    }
    i4 -= 1024 * 512;
    if (i4 < 512 * 1024) {
        float4 s = *(const float4*)(wop + (size_t)i4);
        float4 g = *(const float4*)(rw + (i4 & 1023));
        ushort4 v;
        v.x = f2bf(s.x * g.x); v.y = f2bf(s.y * g.y);
        v.z = f2bf(s.z * g.z); v.w = f2bf(s.w * g.w);
        *(ushort4*)(wopb + i4) = v;
        return;
    }
    i4 -= 512 * 1024;
    if (i4 < 512 * 1024) {
        float4 s = *(const float4*)(w2 + (size_t)i4);
        ushort4 v;
        v.x = f2bf(s.x); v.y = f2bf(s.y); v.z = f2bf(s.z); v.w = f2bf(s.w);
        *(ushort4*)(w2b + i4) = v;
    }
}

// ---------------------------------------------------------------------------
// seg_scan (dt fused)
// ---------------------------------------------------------------------------
__global__ __launch_bounds__(128)
void seg_scan(const ushort* __restrict__ raw, const float* __restrict__ dt_bias,
              const float* __restrict__ A_log, float* __restrict__ dtr,
              float* __restrict__ segb, float* __restrict__ alphab,
              float* __restrict__ Pb)
{
    __shared__ float s[128];
    const int tid = threadIdx.x;
    const int c = blockIdx.x, h = blockIdx.y, b = blockIdx.z;
    const int bh = b * 16 + h;
    const int r = c * QCH + tid;
    const size_t grow = (size_t)b * LSEQ + (LSEQ - 1 - r);
    const size_t idx = (size_t)bh * LSEQ + r;

    float v = bf2f(raw[grow * NPAD + 2176 + h]) + dt_bias[h];
    float dt = (v > 20.f) ? v : log1pf(expf(v));
    float Ah = -expf(A_log[h]);
    s[tid] = dt * Ah;
    __syncthreads();
#pragma unroll
    for (int off = 1; off < 128; off <<= 1) {
        float t = (tid >= off) ? s[tid - off] : 0.f;
        __syncthreads();
        s[tid] += t;
        __syncthreads();
    }
    float seg = s[tid];
    float last = s[127];
    dtr[idx] = dt;
    segb[idx] = seg;
    alphab[idx] = __expf(last - seg) * dt;
    if (tid == 127) Pb[bh * NCH + c] = __expf(last);
}

// ---------------------------------------------------------------------------
// Anti-causal depthwise conv + silu, rolling-window:
// thread = (8-row strip, 8-channel group). Rows loaded once, kept in regs.
// ---------------------------------------------------------------------------
#define CSTRIP 8
__global__ __launch_bounds__(256)
void conv_silu(const ushort* __restrict__ raw, const float* __restrict__ cw,
               const float* __restrict__ cb, ushort* __restrict__ xh,
               ushort* __restrict__ bc)
{
    const int idx = blockIdx.x * 256 + threadIdx.x;   // over (TTOK/CSTRIP)*144
    if (idx >= (TTOK / CSTRIP) * 144) return;
    const int strip = idx / 144;
    const int g = idx - strip * 144;
    const int c0 = g * 8;
    const int row0 = strip * CSTRIP;                  // global first row
    const int l0 = row0 & (LSEQ - 1);

    float wt[4][8];   // wt[j][e]: weight for tap reading row l+j  (= cw[ch][3-j])
    float bias[8];
#pragma unroll
    for (int e = 0; e < 8; ++e) {
        float4 a = *(const float4*)(cw + (c0 + e) * 4);
        wt[0][e] = a.w; wt[1][e] = a.z; wt[2][e] = a.y; wt[3][e] = a.x;
        bias[e] = cb[c0 + e];
    }

    // rolling rows as float[8]; win[(l+j) & 3] holds row l+j
    float win[4][8];
    auto loadrow = [&](int l, float* dst) {   // l relative within sequence
        if (l < LSEQ) {
            ushortx8 v = *(const ushortx8*)(raw + (size_t)(row0 - l0 + l) * NPAD + 1024 + c0);
#pragma unroll
            for (int e = 0; e < 8; ++e) dst[e] = bf2f(v[e]);
        } else {
#pragma unroll
            for (int e = 0; e < 8; ++e) dst[e] = 0.f;
        }
    };

    // iterate l from l0+CSTRIP-1 down to l0; window needs rows l..l+3
    {
        const int ltop = l0 + CSTRIP - 1;
        loadrow(ltop + 1, win[(ltop + 1) & 3]);
        loadrow(ltop + 2, win[(ltop + 2) & 3]);
        loadrow(ltop + 3, win[(ltop + 3) & 3]);
    }
#pragma unroll
    for (int s = CSTRIP - 1; s >= 0; --s) {
        const int l = l0 + s;
        loadrow(l, win[l & 3]);
        ushortx8 o;
#pragma unroll
        for (int e = 0; e < 8; ++e) {
            float acc = bias[e];
#pragma unroll
            for (int j = 0; j < 4; ++j)
                acc = fmaf(wt[j][e], win[(l + j) & 3][e], acc);
            o[e] = f2bf(silu_f(acc));
        }
        const size_t row = (size_t)row0 + s;
        if (c0 < 1024) *(ushortx8*)(xh + row * 1024 + c0) = o;
        else           *(ushortx8*)(bc + row * 128 + (c0 - 1024)) = o;
    }
}

// ---------------------------------------------------------------------------
// SSD pass A: per tile (c,h,b), chunk end-state
//   L[p,n] = sum_tau XT[p,tau] * (alpha(tau)*B[tau,n])
// ---------------------------------------------------------------------------
__global__ __launch_bounds__(256)
void ssd_states(const ushort* __restrict__ xh, const ushort* __restrict__ bc,
                const float* __restrict__ alphab, float* __restrict__ sbuf)
{
    __shared__ __align__(16) ushort XT[64 * 136];
    __shared__ __align__(16) ushort BpT[64 * 136];
    const int tid = threadIdx.x;
    const int w = tid >> 6, lane = tid & 63;
    const int lm = lane & 15, quad = lane >> 4;
    const int c = blockIdx.x, h = blockIdx.y, b = blockIdx.z;
    const int bh = b * 16 + h;
    const size_t abase = (size_t)bh * LSEQ + c * QCH;

#pragma unroll
    for (int it = 0; it < 8; ++it) {
        int idx = it * 256 + tid;
        int tau = idx >> 4, e4 = (idx & 15) * 4;
        size_t grow = (size_t)b * LSEQ + (LSEQ - 1 - (c * QCH + tau));
        ushort4 xv = *(const ushort4*)(xh + grow * 1024 + h * 64 + e4);
        XT[(e4 + 0) * 136 + tau] = xv.x;
        XT[(e4 + 1) * 136 + tau] = xv.y;
        XT[(e4 + 2) * 136 + tau] = xv.z;
        XT[(e4 + 3) * 136 + tau] = xv.w;
        float al = alphab[abase + tau];
        ushort4 bv = *(const ushort4*)(bc + grow * 128 + e4);
        BpT[(e4 + 0) * 136 + tau] = f2bf(bf2f(bv.x) * al);
        BpT[(e4 + 1) * 136 + tau] = f2bf(bf2f(bv.y) * al);
        BpT[(e4 + 2) * 136 + tau] = f2bf(bf2f(bv.z) * al);
        BpT[(e4 + 3) * 136 + tau] = f2bf(bf2f(bv.w) * al);
    }
    __syncthreads();

    floatx4 L[4];
#pragma unroll
    for (int j = 0; j < 4; ++j) L[j] = (floatx4){0.f, 0.f, 0.f, 0.f};
#pragma unroll
    for (int kc = 0; kc < 4; ++kc) {
        short8 a = *(const short8*)(XT + (w * 16 + lm) * 136 + kc * 32 + quad * 8);
#pragma unroll
        for (int jn = 0; jn < 4; ++jn) {
            short8 bf = *(const short8*)(BpT + (jn * 16 + lm) * 136 + kc * 32 + quad * 8);
            L[jn] = __builtin_amdgcn_mfma_f32_16x16x32_bf16(a, bf, L[jn], 0, 0, 0);
        }
    }
    float* Sp = sbuf + ((size_t)bh * NCH + c) * 4096;
#pragma unroll
    for (int jn = 0; jn < 4; ++jn)
#pragma unroll
        for (int r = 0; r < 4; ++r) {
            int p = w * 16 + quad * 4 + r;
            Sp[p * 64 + jn * 16 + lm] = L[jn][r];
        }
}

// ---------------------------------------------------------------------------
// Combine: sequential over chunks in scan (r) order, prefetched.
// Also zeroes the per-row ssq accumulator for the rms fusion.
// ---------------------------------------------------------------------------
__global__ __launch_bounds__(256)
void scan_combine(float* __restrict__ sbuf, const float* __restrict__ Pb,
                  float* __restrict__ ssq)
{
    const int tid = threadIdx.x;
    const int h = blockIdx.y, b = blockIdx.z;
    const int bh = b * 16 + h;
    ssq[(size_t)bh * 256 + tid] = 0.f;
    const int off = tid * 16;
    float carry[16];
#pragma unroll
    for (int j = 0; j < 16; ++j) carry[j] = 0.f;

    float* sp0 = sbuf + (size_t)bh * NCH * 4096 + off;
    float4 n0 = *(const float4*)(sp0 + 0);
    float4 n1 = *(const float4*)(sp0 + 4);
    float4 n2 = *(const float4*)(sp0 + 8);
    float4 n3 = *(const float4*)(sp0 + 12);
    float Pn = Pb[bh * NCH];

    for (int c = 0; c < NCH; ++c) {
        float4 l0 = n0, l1 = n1, l2 = n2, l3 = n3;
        float P = Pn;
        if (c + 1 < NCH) {
            const float* spn = sp0 + (size_t)(c + 1) * 4096;
            n0 = *(const float4*)(spn + 0);
            n1 = *(const float4*)(spn + 4);
            n2 = *(const float4*)(spn + 8);
            n3 = *(const float4*)(spn + 12);
            Pn = Pb[bh * NCH + c + 1];
        }
        float* sp = sp0 + (size_t)c * 4096;
        *(float4*)(sp + 0)  = make_float4(carry[0],  carry[1],  carry[2],  carry[3]);
        *(float4*)(sp + 4)  = make_float4(carry[4],  carry[5],  carry[6],  carry[7]);
        *(float4*)(sp + 8)  = make_float4(carry[8],  carry[9],  carry[10], carry[11]);
        *(float4*)(sp + 12) = make_float4(carry[12], carry[13], carry[14], carry[15]);
        float lv[16] = {l0.x, l0.y, l0.z, l0.w, l1.x, l1.y, l1.z, l1.w,
                        l2.x, l2.y, l2.z, l2.w, l3.x, l3.y, l3.z, l3.w};
#pragma unroll
        for (int j = 0; j < 16; ++j) carry[j] = fmaf(carry[j], P, lv[j]);
    }
}

// ---------------------------------------------------------------------------
// SSD pass C: Y = [M o (C B^T)] X + diag(exp(seg)) C h_start^T, D on diagonal,
// z-gate fused, writes gated bf16 + atomic per-row sum of squares (rms fusion).
// ---------------------------------------------------------------------------
__global__ __launch_bounds__(256)
void ssd_y(const ushort* __restrict__ xh, const ushort* __restrict__ bc,
           const float* __restrict__ segb, const float* __restrict__ dtb_,
           const float* __restrict__ Dvec, const float* __restrict__ sbuf,
           const ushort* __restrict__ zb, ushort* __restrict__ gz,
           float* __restrict__ ssq)
{
    __shared__ __align__(16) char smem[72192];
    ushort* Ct  = (ushort*)smem;            // [128][72]
    ushort* XT  = (ushort*)(smem + 18432);  // [64][136]
    ushort* Bt  = (ushort*)(smem + 35840);  // [128][72]  (dead after GEMM1)
    ushort* Wl  = (ushort*)(smem + 35840);  // [128][136] (overlaps Bt)
    float* segl = (float*)(smem + 70656);   // [128]
    float* dtl  = (float*)(smem + 71168);   // [128]

    const int tid = threadIdx.x;
    const int w = tid >> 6, lane = tid & 63;
    const int lm = lane & 15, quad = lane >> 4;
    const int c = blockIdx.x, h = blockIdx.y, b = blockIdx.z;
    const int bh = b * 16 + h;
    const size_t abase = (size_t)bh * LSEQ + c * QCH;

    if (tid < 128) {
        segl[tid] = segb[abase + tid];
        dtl[tid]  = dtb_[abase + tid];
    }
#pragma unroll
    for (int it = 0; it < 8; ++it) {
        int idx = it * 256 + tid;
        int tau = idx >> 4, e4 = (idx & 15) * 4;
        size_t grow = (size_t)b * LSEQ + (LSEQ - 1 - (c * QCH + tau));
        ushort4 bv = *(const ushort4*)(bc + grow * 128 + e4);
        ushort4 cv = *(const ushort4*)(bc + grow * 128 + 64 + e4);
        *(ushort4*)(Bt + tau * 72 + e4) = bv;
        *(ushort4*)(Ct + tau * 72 + e4) = cv;
        ushort4 xv = *(const ushort4*)(xh + grow * 1024 + h * 64 + e4);
        XT[(e4 + 0) * 136 + tau] = xv.x;
        XT[(e4 + 1) * 136 + tau] = xv.y;
        XT[(e4 + 2) * 136 + tau] = xv.z;
        XT[(e4 + 3) * 136 + tau] = xv.w;
    }
    __syncthreads();

    // GEMM1: G = C . B^T ; wave w owns rows [w*32,+32)
    floatx4 G[2][8];
#pragma unroll
    for (int i = 0; i < 2; ++i)
#pragma unroll
        for (int j = 0; j < 8; ++j) G[i][j] = (floatx4){0.f, 0.f, 0.f, 0.f};
#pragma unroll
    for (int kc = 0; kc < 2; ++kc) {
        short8 a[2];
#pragma unroll
        for (int i = 0; i < 2; ++i)
            a[i] = *(const short8*)(Ct + (w * 32 + i * 16 + lm) * 72 + kc * 32 + quad * 8);
#pragma unroll
        for (int jn = 0; jn < 8; ++jn) {
            short8 bf = *(const short8*)(Bt + (jn * 16 + lm) * 72 + kc * 32 + quad * 8);
#pragma unroll
            for (int i = 0; i < 2; ++i)
                G[i][jn] = __builtin_amdgcn_mfma_f32_16x16x32_bf16(a[i], bf, G[i][jn], 0, 0, 0);
        }
    }
    __syncthreads();   // everyone done reading Bt before Wl overwrites it

    const float Dh = Dvec[h];
#pragma unroll
    for (int i = 0; i < 2; ++i) {
        const int taub = w * 32 + i * 16;
#pragma unroll
        for (int jn = 0; jn < 8; ++jn) {
            const int sigma = jn * 16 + lm;
            const float dts = dtl[sigma];
            const float segs = segl[sigma];
#pragma unroll
            for (int r = 0; r < 4; ++r) {
                const int tau = taub + quad * 4 + r;
                float g = G[i][jn][r];
                float wv;
                if (sigma < tau)       wv = dts * g * __expf(segl[tau] - segs);
                else if (sigma == tau) wv = dts * g + Dh;
                else                   wv = 0.f;
                Wl[tau * 136 + sigma] = f2bf(wv);
            }
        }
    }
    // no barrier needed: each wave reads back only its own W rows

    // GEMM2: Y = W.X + (exp(seg) C).H^T
    floatx4 Y[2][4];
#pragma unroll
    for (int i = 0; i < 2; ++i)
#pragma unroll
        for (int j = 0; j < 4; ++j) Y[i][j] = (floatx4){0.f, 0.f, 0.f, 0.f};
#pragma unroll
    for (int kc = 0; kc < 4; ++kc) {
        short8 a[2];
#pragma unroll
        for (int i = 0; i < 2; ++i)
            a[i] = *(const short8*)(Wl + (w * 32 + i * 16 + lm) * 136 + kc * 32 + quad * 8);
#pragma unroll
        for (int jn = 0; jn < 4; ++jn) {
            short8 bf = *(const short8*)(XT + (jn * 16 + lm) * 136 + kc * 32 + quad * 8);
#pragma unroll
            for (int i = 0; i < 2; ++i)
                Y[i][jn] = __builtin_amdgcn_mfma_f32_16x16x32_bf16(a[i], bf, Y[i][jn], 0, 0, 0);
        }
    }
    const float* Hp = sbuf + ((size_t)bh * NCH + c) * 4096;
#pragma unroll
    for (int kc = 0; kc < 2; ++kc) {
        short8 a[2];
#pragma unroll
        for (int i = 0; i < 2; ++i) {
            const int row = w * 32 + i * 16 + lm;
            const float es = __expf(segl[row]);
            short8 craw = *(const short8*)(Ct + row * 72 + kc * 32 + quad * 8);
#pragma unroll
            for (int e = 0; e < 8; ++e)
                a[i][e] = (short)f2bf(bf2f((ushort)craw[e]) * es);
        }
#pragma unroll
        for (int jn = 0; jn < 4; ++jn) {
            const float* hp = Hp + (jn * 16 + lm) * 64 + kc * 32 + quad * 8;
            float4 h0 = *(const float4*)(hp);
            float4 h1 = *(const float4*)(hp + 4);
            short8 bf;
            bf[0] = (short)f2bf(h0.x); bf[1] = (short)f2bf(h0.y);
            bf[2] = (short)f2bf(h0.z); bf[3] = (short)f2bf(h0.w);
            bf[4] = (short)f2bf(h1.x); bf[5] = (short)f2bf(h1.y);
            bf[6] = (short)f2bf(h1.z); bf[7] = (short)f2bf(h1.w);
#pragma unroll
            for (int i = 0; i < 2; ++i)
                Y[i][jn] = __builtin_amdgcn_mfma_f32_16x16x32_bf16(a[i], bf, Y[i][jn], 0, 0, 0);
        }
    }

    // epilogue: z-gate, store gated bf16, accumulate per-row sum of squares
#pragma unroll
    for (int i = 0; i < 2; ++i) {
#pragma unroll
        for (int r = 0; r < 4; ++r) {
            const int tau = w * 32 + i * 16 + quad * 4 + r;
            const size_t grow = (size_t)b * LSEQ + (LSEQ - 1 - (c * QCH + tau));
            float part = 0.f;
#pragma unroll
            for (int jn = 0; jn < 4; ++jn) {
                const int col = h * 64 + jn * 16 + lm;
                float yv = Y[i][jn][r];
                float zv = bf2f(zb[grow * NPAD + col]);
                float gv = yv * silu_f(zv);
                gz[grow * 1024 + col] = f2bf(gv);
                part += gv * gv;
            }
            part += __shfl_xor(part, 1);
            part += __shfl_xor(part, 2);
            part += __shfl_xor(part, 4);
            part += __shfl_xor(part, 8);
            if (lm == 0) atomicAdd(ssq + grow, part);
        }
    }
}

// ---------------------------------------------------------------------------
// LayerNorm over 512, fp32 in, bf16 out
// ---------------------------------------------------------------------------
__global__ __launch_bounds__(256)
void layernorm_k(const float* __restrict__ x, const float* __restrict__ gg,
                 const float* __restrict__ bb, ushort* __restrict__ out)
{
    const int row = blockIdx.x;
    const int tid = threadIdx.x;
    float x0 = x[(size_t)row * 512 + tid];
    float x1 = x[(size_t)row * 512 + 256 + tid];
    float s = x0 + x1, ss = x0 * x0 + x1 * x1;
#pragma unroll
    for (int off = 32; off > 0; off >>= 1) {
        s += __shfl_xor(s, off);
        ss += __shfl_xor(ss, off);
    }
    __shared__ float rs[4], rss[4];
    if ((tid & 63) == 0) { rs[tid >> 6] = s; rss[tid >> 6] = ss; }
    __syncthreads();
    s = rs[0] + rs[1] + rs[2] + rs[3];
    ss = rss[0] + rss[1] + rss[2] + rss[3];
    const float mean = s * (1.f / 512.f);
    const float var = ss * (1.f / 512.f) - mean * mean;
    const float inv = rsqrtf(var + 1e-5f);
    out[(size_t)row * 512 + tid]       = f2bf((x0 - mean) * inv * gg[tid] + bb[tid]);
    out[(size_t)row * 512 + 256 + tid] = f2bf((x1 - mean) * inv * gg[256 + tid] + bb[256 + tid]);
}

// ---------------------------------------------------------------------------
extern "C" void kernel_launch(void* const* d_in, const int* in_sizes, int n_in,
                              void* d_out, int out_size, void* d_ws, size_t ws_size,
                              hipStream_t stream)
{
    const float* x         = (const float*)d_in[0];
    const float* in_proj_w = (const float*)d_in[1];   // (2192, 512)
    const float* conv_w    = (const float*)d_in[2];   // (1152, 4)
    const float* conv_b    = (const float*)d_in[3];
    const float* dt_bias   = (const float*)d_in[4];   // (16,)
    const float* A_log     = (const float*)d_in[5];
    const float* Dv        = (const float*)d_in[6];
    const float* rms_w     = (const float*)d_in[7];
    const float* out_proj_w= (const float*)d_in[8];   // (512, 1024)
    const float* ln_g      = (const float*)d_in[9];
    const float* ln_b      = (const float*)d_in[10];
    const float* w1        = (const float*)d_in[11];  // (1024, 1024)
    const float* b1        = (const float*)d_in[12];
    const float* w2        = (const float*)d_in[13];  // (512, 1024)
    const float* b2        = (const float*)d_in[14];
    float* out = (float*)d_out;
    char* base = (char*)d_ws;

    // workspace layout (byte offsets), liveness-safe reuse:
    ushort* g1out = (ushort*)(base);                   // [T,2304] bf16   75.5 MB
    ushort* xh_b  = (ushort*)(base + 75497472);        // [T,1024] bf16   33.5 MB
    ushort* bc_b  = (ushort*)(base + 109051904);       // [T,128]  bf16    4.2 MB
    ushort* gz    = (ushort*)(base + 113246208);       // [T,1024] bf16   33.5 MB
    ushort* xbf   = (ushort*)(base + 113246208);       // [T,512] bf16 (dead before gz)
    float*  dtr   = (float*) (base + 146800640);       // [64][4096]       1 MB
    float*  segb  = (float*) (base + 148897792);       // [64][4096]       1 MB
    float*  alphab= (float*) (base + 149946368);       // [64][4096]       1 MB
    ushort* wip   = (ushort*)(base + 150994944);       // [2304,512] bf16
    ushort* w1eb  = (ushort*)(base + 153354240);       // [1024,512] bf16
    ushort* wopb  = (ushort*)(base + 154402816);       // [512,1024] bf16
    ushort* w2b   = (ushort*)(base + 155451392);       // [512,1024] bf16
    float*  Pbuf  = (float*) (base + 156499968);       // [2048]
    float*  ssqp  = (float*) (base + 156508160);       // [16384] rms partials
    // post-scan reuse:
    float*  y2  = (float*)base;                        // [T,512] f32 (g1out dead)
    ushort* yln = (ushort*)(base + 33554432);          // [T,512] bf16
    ushort* h1  = gz;                                  // [T,1024] bf16 (gz dead after out_proj)
    // chunk states: 64 tiles/seq-head x 4096 f32 == out_size; d_out dead until MLP2
    float* sbuf = out;

    // ---- casts ----
    cast_x_k<<<(TTOK * 512 / 4 + 255) / 256, 256, 0, stream>>>(
        (const float4*)x, (ushort4*)xbf, TTOK * 512 / 4);
    prep_weights<<<((NPAD * 512 + 1024 * 512 + 2 * 512 * 1024) / 4 + 255) / 256, 256, 0, stream>>>(
        in_proj_w, w1, out_proj_w, w2, rms_w, wip, w1eb, wopb, w2b);

    // ---- in_proj ----
    gemm_mfma<0, ushort><<<dim3(NPAD / 128, TTOK / 128), 256, 0, stream>>>(
        xbf, wip, nullptr, nullptr, g1out, TTOK, NPAD, 512);

    seg_scan<<<dim3(NCH, 16, 4), 128, 0, stream>>>(g1out, dt_bias, A_log, dtr, segb, alphab, Pbuf);
    conv_silu<<<((TTOK / CSTRIP) * 144 + 255) / 256, 256, 0, stream>>>(
        g1out, conv_w, conv_b, xh_b, bc_b);

    // ---- SSD chunked scan ----
    ssd_states  <<<dim3(NCH, 16, 4), 256, 0, stream>>>(xh_b, bc_b, alphab, sbuf);
    scan_combine<<<dim3(1, 16, 4),   256, 0, stream>>>(sbuf, Pbuf, ssqp);
    ssd_y       <<<dim3(NCH, 16, 4), 256, 0, stream>>>(xh_b, bc_b, segb, dtr, Dv,
                                                       sbuf, g1out, gz, ssqp);

    // ---- projections + MLP (rms fused into out_proj) ----
    gemm_mfma<2, float><<<dim3(512 / 128, TTOK / 128), 256, 0, stream>>>(
        gz, wopb, nullptr, ssqp, y2, TTOK, 512, 1024);
    layernorm_k<<<TTOK, 256, 0, stream>>>(y2, ln_g, ln_b, yln);
    gemm_mfma<1, ushort><<<dim3(1024 / 128, TTOK / 128), 256, 0, stream>>>(
        yln, w1eb, b1, nullptr, h1, TTOK, 1024, 512);
    gemm_mfma<0, float><<<dim3(512 / 128, TTOK / 128), 256, 0, stream>>>(
        h1, w2b, b2, nullptr, out, TTOK, 512, 1024);
}